// Round 4
// baseline (14.725 us; speedup 1.0000x reference)
//
#include <hip/hip_runtime.h>

// Problem constants (B,C,H,W,L) = (4,16,256,256,25)
#define HWPIX 65536   // H*W
#define NCH   16
#define NLBL  25

// LDS weight layout (b128): w4[k][l] = weight[l][flat 4k..4k+3] where
// flat = o*16+c, so k = o*4 + q (q = c/4).  One ds_read_b128 per (o,q,label).
// Bank of w4[k][l] = 4l % 32: labels alias in groups {l,l+8,l+16,l+24} ->
// <=4 distinct words/bank per instr (~= conflict-free b128 cost); same-label
// lanes broadcast.
__global__ __launch_bounds__(256) void invconv_kernel(
    const float* __restrict__ x,
    const int*   __restrict__ labels,
    const float* __restrict__ weight,
    const float* __restrict__ bias,
    float*       __restrict__ out)
{
    __shared__ float4 w4[64][32];   // 32 KiB

    const int tid = threadIdx.x;

    // One pixel per thread: 262144 threads = 4096 waves = 16 waves/CU.
    const int t = blockIdx.x * 256 + tid;
    const int b = t >> 16;               // / HWPIX
    const int p = t & 65535;             // % HWPIX

    // Issue label + x loads BEFORE staging so HBM latency overlaps it.
    const int l0 = labels[b * HWPIX + p];

    float xv[NCH];
    const float* xb = x + b * (NCH * HWPIX) + p;
    #pragma unroll
    for (int c = 0; c < NCH; ++c)
        xv[c] = xb[c * HWPIX];           // 4B/lane, coalesced 256B/wave-instr

    // Stage weights: 2048 float4 slots used, flat = k*32 + l.
    #pragma unroll
    for (int i = 0; i < 8; ++i) {
        int flat = tid + i * 256;        // < 2048
        int l = flat & 31;
        int k = flat >> 5;               // 0..63
        if (l < NLBL) {
            w4[k][l] = *reinterpret_cast<const float4*>(weight + l * 256 + k * 4);
        }
    }
    __syncthreads();

    const float bias0 = bias[l0];

    float* ob = out + b * (NCH * HWPIX) + p;
    #pragma unroll
    for (int o = 0; o < NCH; ++o) {
        float acc0 = bias0;
        #pragma unroll
        for (int q = 0; q < 4; ++q) {
            const float4 wa = w4[o * 4 + q][l0];
            acc0 = fmaf(wa.x, xv[4 * q + 0], acc0);
            acc0 = fmaf(wa.y, xv[4 * q + 1], acc0);
            acc0 = fmaf(wa.z, xv[4 * q + 2], acc0);
            acc0 = fmaf(wa.w, xv[4 * q + 3], acc0);
        }
        ob[o * HWPIX] = acc0;
    }
}

extern "C" void kernel_launch(void* const* d_in, const int* in_sizes, int n_in,
                              void* d_out, int out_size, void* d_ws, size_t ws_size,
                              hipStream_t stream) {
    const float* x      = (const float*)d_in[0];
    const int*   labels = (const int*)  d_in[1];
    const float* weight = (const float*)d_in[2];
    const float* bias   = (const float*)d_in[3];
    float*       out    = (float*)d_out;

    // total pixels = 262144; 1 px/thread, 256 threads/block -> 1024 blocks
    dim3 grid(1024), block(256);
    invconv_kernel<<<grid, block, 0, stream>>>(x, labels, weight, bias, out);
}